// Round 1
// baseline (531.708 us; speedup 1.0000x reference)
//
#include <hip/hip_runtime.h>
#include <math.h>

typedef float  float4_t __attribute__((ext_vector_type(4)));
typedef _Float16 half8  __attribute__((ext_vector_type(8)));
typedef _Float16 half4_t __attribute__((ext_vector_type(4)));

#define NEG_BIG (-1.0e12f)

// ---------------- Kernel A: h = inp @ W  (fp32, M=16384 K=256 N=128) ----------
// 64 rows/block, K-chunks of 64. Thread: 4 rows x 8 feats (32 acc).
__global__ __launch_bounds__(256) void k_gemm_h(const float* __restrict__ inp,
                                                const float* __restrict__ W,
                                                float* __restrict__ h) {
    __shared__ float sA[64 * 68];   // stride 68 (272B, 16B-aligned rows, conflict-free)
    __shared__ float sW[64 * 128];
    const int t   = threadIdx.x;
    const int gr0 = blockIdx.x * 64;
    const int f0  = (t & 15) * 8;
    const int r0  = (t >> 4) * 4;
    float4_t acc0[4] = {}; float4_t acc1[4] = {};
    for (int kc = 0; kc < 4; ++kc) {
        __syncthreads();
        #pragma unroll
        for (int it = 0; it < 4; ++it) {           // stage inp 64x64
            int fi = it * 256 + t; int r = fi >> 4; int c = (fi & 15) * 4;
            *(float4_t*)&sA[r * 68 + c] =
                *(const float4_t*)&inp[(size_t)(gr0 + r) * 256 + kc * 64 + c];
        }
        #pragma unroll
        for (int it = 0; it < 8; ++it) {           // stage W 64x128
            int fi = it * 256 + t; int k = fi >> 5; int c = (fi & 31) * 4;
            *(float4_t*)&sW[k * 128 + c] =
                *(const float4_t*)&W[(size_t)(kc * 64 + k) * 128 + c];
        }
        __syncthreads();
        for (int k = 0; k < 64; ++k) {
            float4_t w0 = *(const float4_t*)&sW[k * 128 + f0];
            float4_t w1 = *(const float4_t*)&sW[k * 128 + f0 + 4];
            #pragma unroll
            for (int r = 0; r < 4; ++r) {
                float av = sA[(r0 + r) * 68 + k];
                acc0[r] += av * w0; acc1[r] += av * w1;
            }
        }
    }
    #pragma unroll
    for (int r = 0; r < 4; ++r) {
        *(float4_t*)&h[(size_t)(gr0 + r0 + r) * 128 + f0]     = acc0[r];
        *(float4_t*)&h[(size_t)(gr0 + r0 + r) * 128 + f0 + 4] = acc1[r];
    }
}

// ---------------- Kernel B: s1/s2 = h . a1 / h . a2 ---------------------------
__global__ __launch_bounds__(128) void k_s1s2(const float* __restrict__ h,
                                              const float* __restrict__ a,
                                              float* __restrict__ s1,
                                              float* __restrict__ s2) {
    const int t  = threadIdx.x;
    const int gr = blockIdx.x;
    float v  = h[(size_t)gr * 128 + t];
    float p1 = v * a[t];
    float p2 = v * a[128 + t];
    #pragma unroll
    for (int o = 32; o > 0; o >>= 1) { p1 += __shfl_down(p1, o); p2 += __shfl_down(p2, o); }
    __shared__ float r1[2], r2[2];
    if ((t & 63) == 0) { r1[t >> 6] = p1; r2[t >> 6] = p2; }
    __syncthreads();
    if (t == 0) { s1[gr] = r1[0] + r1[1]; s2[gr] = r2[0] + r2[1]; }
}

// ---------------- Kernel T: hT[b][f][n] = fp16(h[b][n][f]) --------------------
__global__ __launch_bounds__(256) void k_transpose(const float* __restrict__ h,
                                                   _Float16* __restrict__ hT) {
    __shared__ float s[64 * 33];
    const int bi = blockIdx.x;
    const int b  = bi >> 8; const int rem = bi & 255;
    const int n0 = (rem >> 2) * 64; const int f0 = (rem & 3) * 32;
    const int t  = threadIdx.x;
    #pragma unroll
    for (int it = 0; it < 8; ++it) {
        int idx = it * 256 + t; int n = idx >> 5; int f = idx & 31;
        s[n * 33 + f] = h[(size_t)(b * 4096 + n0 + n) * 128 + f0 + f];
    }
    __syncthreads();
    #pragma unroll
    for (int it = 0; it < 8; ++it) {
        int idx = it * 256 + t; int f = idx >> 6; int n = idx & 63;
        hT[(size_t)b * 128 * 4096 + (size_t)(f0 + f) * 4096 + n0 + n] =
            (_Float16)s[n * 33 + f];
    }
}

// ---------------- Kernel F: fused online-softmax attention + P@H (fp16 MFMA) --
// Block: 64 query rows x 2048-wide j-range (j-split=2). 4 waves, each wave owns
// a 16-row m-tile and all 8 n-tiles (Fout=128). j-tiles of 64 (K-chunks of 32).
#define PSTR 72   // LDS row stride in halves: 144 B = 16B-aligned, ~2-way banks

__global__ __launch_bounds__(256, 2) void k_flash(const float* __restrict__ adj,
                                                  const _Float16* __restrict__ hT,
                                                  const float* __restrict__ s1,
                                                  const float* __restrict__ s2,
                                                  float* __restrict__ part_acc,
                                                  float* __restrict__ part_m,
                                                  float* __restrict__ part_l) {
    __shared__ _Float16 hT_lds[128 * PSTR];
    __shared__ _Float16 p_lds[64 * PSTR];
    __shared__ float m_lds[64], l_lds[64], al_lds[64];

    const int t   = threadIdx.x;
    const int bid = blockIdx.x;
    const int sp  = bid & 1;           // j-split index
    const int rb  = (bid >> 1) & 63;   // row-block
    const int b   = bid >> 7;          // batch
    const int i0    = rb * 64;
    const int jbase = sp * 2048;
    const float*    adj_b = adj + (size_t)b * 4096 * 4096;
    const _Float16* hT_b  = hT  + (size_t)b * 128 * 4096;
    const float*    s1_b  = s1 + b * 4096;
    const float*    s2_b  = s2 + b * 4096;

    if (t < 64) { m_lds[t] = -INFINITY; l_lds[t] = 0.f; }

    const int lane = t & 63, w = t >> 6;
    const int quad = lane >> 4, ln15 = lane & 15;
    const int c0   = (t & 15) * 4;     // col group within j-tile
    const int rgrp = t >> 4;           // 0..15 row-group
    float s1r[4];
    #pragma unroll
    for (int it = 0; it < 4; ++it) s1r[it] = s1_b[i0 + it * 16 + rgrp];

    float4_t acc[8] = {};
    __syncthreads();

    for (int jt = 0; jt < 32; ++jt) {
        const int j0 = jbase + jt * 64;
        // ---- stage hT tile [128 f][64 j] (fp16) ----
        #pragma unroll
        for (int it = 0; it < 4; ++it) {
            int fi = it * 256 + t; int f = fi >> 3; int j8 = fi & 7;
            *(half8*)&hT_lds[f * PSTR + j8 * 8] =
                *(const half8*)&hT_b[(size_t)f * 4096 + j0 + j8 * 8];
        }
        // ---- att / online-softmax phase (each 16-lane group owns a row) ----
        float4_t s2v = *(const float4_t*)&s2_b[j0 + c0];
        #pragma unroll
        for (int it = 0; it < 4; ++it) {
            const int r = it * 16 + rgrp;
            float4_t av = *(const float4_t*)&adj_b[(size_t)(i0 + r) * 4096 + j0 + c0];
            float e0 = s1r[it] + s2v[0]; e0 = e0 > 0.f ? e0 : 0.2f * e0;
            float e1 = s1r[it] + s2v[1]; e1 = e1 > 0.f ? e1 : 0.2f * e1;
            float e2 = s1r[it] + s2v[2]; e2 = e2 > 0.f ? e2 : 0.2f * e2;
            float e3 = s1r[it] + s2v[3]; e3 = e3 > 0.f ? e3 : 0.2f * e3;
            float att0 = av[0] > 0.f ? av[0] * e0 : NEG_BIG;
            float att1 = av[1] > 0.f ? av[1] * e1 : NEG_BIG;
            float att2 = av[2] > 0.f ? av[2] * e2 : NEG_BIG;
            float att3 = av[3] > 0.f ? av[3] * e3 : NEG_BIG;
            float tmax = fmaxf(fmaxf(att0, att1), fmaxf(att2, att3));
            #pragma unroll
            for (int msk = 1; msk < 16; msk <<= 1) tmax = fmaxf(tmax, __shfl_xor(tmax, msk));
            float m_old = m_lds[r];
            float m_new = fmaxf(m_old, tmax);
            float al    = expf(m_old - m_new);   // -inf first tile -> 0
            float p0 = expf(att0 - m_new), p1 = expf(att1 - m_new);
            float p2 = expf(att2 - m_new), p3 = expf(att3 - m_new);
            _Float16 q0 = (_Float16)p0, q1 = (_Float16)p1;
            _Float16 q2 = (_Float16)p2, q3 = (_Float16)p3;
            // l summed from fp16-rounded p for consistency with MFMA accumulator
            float psum = (float)q0 + (float)q1 + (float)q2 + (float)q3;
            #pragma unroll
            for (int msk = 1; msk < 16; msk <<= 1) psum += __shfl_xor(psum, msk);
            half4_t qv = {q0, q1, q2, q3};
            *(half4_t*)&p_lds[r * PSTR + c0] = qv;
            if ((t & 15) == 0) {
                m_lds[r]  = m_new;
                al_lds[r] = al;
                l_lds[r]  = l_lds[r] * al + psum;
            }
        }
        __syncthreads();
        // ---- MFMA phase: rescale acc, then acc += P(16x64) @ H(64x128) ----
        float alr[4];
        #pragma unroll
        for (int reg = 0; reg < 4; ++reg) alr[reg] = al_lds[w * 16 + quad * 4 + reg];
        #pragma unroll
        for (int nt = 0; nt < 8; ++nt) {
            acc[nt][0] *= alr[0]; acc[nt][1] *= alr[1];
            acc[nt][2] *= alr[2]; acc[nt][3] *= alr[3];
        }
        half8 afrag[2];
        #pragma unroll
        for (int kc = 0; kc < 2; ++kc)
            afrag[kc] = *(const half8*)&p_lds[(w * 16 + ln15) * PSTR + kc * 32 + quad * 8];
        #pragma unroll
        for (int nt = 0; nt < 8; ++nt) {
            #pragma unroll
            for (int kc = 0; kc < 2; ++kc) {
                half8 bfrag = *(const half8*)&hT_lds[(nt * 16 + ln15) * PSTR + kc * 32 + quad * 8];
                acc[nt] = __builtin_amdgcn_mfma_f32_16x16x32_f16(afrag[kc], bfrag, acc[nt], 0, 0, 0);
            }
        }
        __syncthreads();
    }
    // ---- epilogue: write unnormalized partials ----
    const size_t rowbase = (size_t)sp * 16384 + (size_t)b * 4096 + i0;
    #pragma unroll
    for (int nt = 0; nt < 8; ++nt) {
        #pragma unroll
        for (int reg = 0; reg < 4; ++reg) {
            int r = w * 16 + quad * 4 + reg;
            part_acc[(rowbase + r) * 128 + nt * 16 + ln15] = acc[nt][reg];
        }
    }
    if (t < 64) {
        part_m[rowbase + t] = m_lds[t];
        part_l[rowbase + t] = l_lds[t];
    }
}

// ---------------- Kernel E: merge 2 j-split partials + elu --------------------
__global__ __launch_bounds__(256) void k_combine(const float* __restrict__ part_acc,
                                                 const float* __restrict__ part_m,
                                                 const float* __restrict__ part_l,
                                                 float* __restrict__ out) {
    const int tid = blockIdx.x * 256 + threadIdx.x;
    const int gr  = tid >> 7; const int f = tid & 127;
    float m0 = part_m[gr], m1 = part_m[16384 + gr];
    float l0 = part_l[gr], l1 = part_l[16384 + gr];
    float a0 = part_acc[(size_t)gr * 128 + f];
    float a1 = part_acc[(size_t)(16384 + gr) * 128 + f];
    float M  = fmaxf(m0, m1);
    float w0 = expf(m0 - M), w1 = expf(m1 - M);
    float v  = (w0 * a0 + w1 * a1) / (w0 * l0 + w1 * l1);
    out[tid] = v > 0.f ? v : expm1f(v);
}

extern "C" void kernel_launch(void* const* d_in, const int* in_sizes, int n_in,
                              void* d_out, int out_size, void* d_ws, size_t ws_size,
                              hipStream_t stream) {
    const float* inp = (const float*)d_in[0];   // (4,4096,256)
    const float* adj = (const float*)d_in[1];   // (4,4096,4096)
    const float* W   = (const float*)d_in[2];   // (256,128)
    const float* a   = (const float*)d_in[3];   // (256,1)
    float* out = (float*)d_out;                 // (4,4096,128)

    char* wsb = (char*)d_ws;
    float*    h        = (float*)(wsb);                  // 8 MB
    _Float16* hT       = (_Float16*)(wsb + 8388608);     // 4 MB
    float*    s1       = (float*)(wsb + 12582912);       // 64 KB
    float*    s2       = (float*)(wsb + 12648448);       // 64 KB
    float*    part_m   = (float*)(wsb + 12713984);       // 128 KB
    float*    part_l   = (float*)(wsb + 12845056);       // 128 KB
    float*    part_acc = (float*)(wsb + 12976128);       // 16 MB  (total ~28.4 MB)

    hipLaunchKernelGGL(k_gemm_h,   dim3(256),   dim3(256), 0, stream, inp, W, h);
    hipLaunchKernelGGL(k_s1s2,     dim3(16384), dim3(128), 0, stream, h, a, s1, s2);
    hipLaunchKernelGGL(k_transpose,dim3(1024),  dim3(256), 0, stream, h, hT);
    hipLaunchKernelGGL(k_flash,    dim3(512),   dim3(256), 0, stream, adj, hT, s1, s2,
                       part_acc, part_m, part_l);
    hipLaunchKernelGGL(k_combine,  dim3(8192),  dim3(256), 0, stream, part_acc, part_m, part_l, out);
}

// Round 2
// 514.766 us; speedup vs baseline: 1.0329x; 1.0329x over previous
//
#include <hip/hip_runtime.h>
#include <math.h>

typedef float    float4_t __attribute__((ext_vector_type(4)));
typedef _Float16 half8    __attribute__((ext_vector_type(8)));

#define NEG_BIG (-1.0e12f)

// ---------------- Kernel P: fused h-GEMM + s1/s2 + hT(fp16) ------------------
// 512 blocks x 256 threads; block = 32 rows of h. h never hits memory:
// epilogue emits s1,s2 (dot with a) and transposed fp16 hT only.
__global__ __launch_bounds__(256) void k_prep(const float* __restrict__ inp,
                                              const float* __restrict__ W,
                                              const float* __restrict__ a,
                                              float* __restrict__ s1,
                                              float* __restrict__ s2,
                                              _Float16* __restrict__ hT) {
    __shared__ float sA[32 * 68];
    __shared__ float sW[64 * 128];
    const int t   = threadIdx.x;
    const int gr0 = blockIdx.x * 32;          // global row base (0..16383)
    const int b   = gr0 >> 12;                // batch
    const int f0  = (t & 15) * 8;
    const int r0  = (t >> 4) * 2;
    float4_t acc0[2] = {}; float4_t acc1[2] = {};
    for (int kc = 0; kc < 4; ++kc) {
        __syncthreads();
        #pragma unroll
        for (int it = 0; it < 2; ++it) {      // stage inp 32x64
            int fi = it * 256 + t; int r = fi >> 4; int c = (fi & 15) * 4;
            *(float4_t*)&sA[r * 68 + c] =
                *(const float4_t*)&inp[(size_t)(gr0 + r) * 256 + kc * 64 + c];
        }
        #pragma unroll
        for (int it = 0; it < 8; ++it) {      // stage W 64x128
            int fi = it * 256 + t; int k = fi >> 5; int c = (fi & 31) * 4;
            *(float4_t*)&sW[k * 128 + c] =
                *(const float4_t*)&W[(size_t)(kc * 64 + k) * 128 + c];
        }
        __syncthreads();
        for (int k = 0; k < 64; ++k) {
            float4_t w0 = *(const float4_t*)&sW[k * 128 + f0];
            float4_t w1 = *(const float4_t*)&sW[k * 128 + f0 + 4];
            #pragma unroll
            for (int r = 0; r < 2; ++r) {
                float av = sA[(r0 + r) * 68 + k];
                acc0[r] += av * w0; acc1[r] += av * w1;
            }
        }
    }
    // epilogue: hT store + s1/s2 row dots (16-lane groups own a row)
    float4_t a1lo = *(const float4_t*)&a[f0];
    float4_t a1hi = *(const float4_t*)&a[f0 + 4];
    float4_t a2lo = *(const float4_t*)&a[128 + f0];
    float4_t a2hi = *(const float4_t*)&a[128 + f0 + 4];
    #pragma unroll
    for (int r = 0; r < 2; ++r) {
        const int row  = gr0 + r0 + r;
        const int rloc = row & 4095;
        #pragma unroll
        for (int c = 0; c < 4; ++c) {
            hT[(size_t)b * (128 * 4096) + (size_t)(f0 + c) * 4096 + rloc]     = (_Float16)acc0[r][c];
            hT[(size_t)b * (128 * 4096) + (size_t)(f0 + 4 + c) * 4096 + rloc] = (_Float16)acc1[r][c];
        }
        float p1 = acc0[r][0]*a1lo[0] + acc0[r][1]*a1lo[1] + acc0[r][2]*a1lo[2] + acc0[r][3]*a1lo[3]
                 + acc1[r][0]*a1hi[0] + acc1[r][1]*a1hi[1] + acc1[r][2]*a1hi[2] + acc1[r][3]*a1hi[3];
        float p2 = acc0[r][0]*a2lo[0] + acc0[r][1]*a2lo[1] + acc0[r][2]*a2lo[2] + acc0[r][3]*a2lo[3]
                 + acc1[r][0]*a2hi[0] + acc1[r][1]*a2hi[1] + acc1[r][2]*a2hi[2] + acc1[r][3]*a2hi[3];
        #pragma unroll
        for (int o = 1; o < 16; o <<= 1) { p1 += __shfl_xor(p1, o); p2 += __shfl_xor(p2, o); }
        if ((t & 15) == 0) { s1[row] = p1; s2[row] = p2; }
    }
}

// ---------------- Kernel M: per-batch s2 max ---------------------------------
__global__ __launch_bounds__(256) void k_s2max(const float* __restrict__ s2,
                                               float* __restrict__ s2max) {
    const int b = blockIdx.x, t = threadIdx.x;
    float m = -INFINITY;
    for (int i = t; i < 4096; i += 256) m = fmaxf(m, s2[b * 4096 + i]);
    #pragma unroll
    for (int o = 1; o < 64; o <<= 1) m = fmaxf(m, __shfl_xor(m, o));
    __shared__ float sm[4];
    if ((t & 63) == 0) sm[t >> 6] = m;
    __syncthreads();
    if (t == 0) s2max[b] = fmaxf(fmaxf(sm[0], sm[1]), fmaxf(sm[2], sm[3]));
}

// ---------------- Kernel F: barrier-free fixed-max attention + P@H -----------
// Grid 1024 blocks x 256 thr. Wave = 16 rows x 1024-j-range (j-split 4).
// No LDS, no __syncthreads: p computed in registers directly in MFMA A-layout;
// B-frags read from global hT (L1-shared across the block's 4 waves).
// mhat_i = max(0, s1_i + max_j s2_j) >= every logit of row i (adj in [0,1)),
// so partials across j-splits are plain sums.
__global__ __launch_bounds__(256, 4) void k_flash(const float* __restrict__ adj,
                                                  const _Float16* __restrict__ hT,
                                                  const float* __restrict__ s1,
                                                  const float* __restrict__ s2,
                                                  const float* __restrict__ s2max,
                                                  float* __restrict__ part_acc,
                                                  float* __restrict__ part_l) {
    const int t    = threadIdx.x;
    const int bid  = blockIdx.x;
    const int sp   = bid & 3;                 // j-split
    const int rb   = (bid >> 2) & 63;         // 64-row block within batch
    const int b    = bid >> 8;                // batch
    const int w    = t >> 6, lane = t & 63;
    const int quad = lane >> 4, ln15 = lane & 15;
    const int rowb  = rb * 64 + w * 16;       // wave's row base within batch
    const int myrow = rowb + ln15;            // this lane's A-row
    const float*    adj_r = adj + (size_t)b * 4096 * 4096 + (size_t)myrow * 4096;
    const _Float16* hT_b  = hT + (size_t)b * 128 * 4096;
    const float*    s2_b  = s2 + b * 4096;
    const float s1v  = s1[b * 4096 + myrow];
    const float mhat = fmaxf(0.f, s1v + s2max[b]);
    const int jwbase = sp * 1024;
    const int coff   = quad * 8;              // this lane's col offset in a 64-tile

    float4_t acc[8] = {};
    float psum = 0.f;

    float4_t adjc[4], adjn[4];
    #pragma unroll
    for (int kc = 0; kc < 2; ++kc) {
        adjc[kc * 2 + 0] = *(const float4_t*)&adj_r[jwbase + kc * 32 + coff];
        adjc[kc * 2 + 1] = *(const float4_t*)&adj_r[jwbase + kc * 32 + coff + 4];
    }
    for (int jt = 0; jt < 16; ++jt) {
        const int j0 = jwbase + jt * 64;
        if (jt < 15) {                        // prefetch next tile's adj
            #pragma unroll
            for (int kc = 0; kc < 2; ++kc) {
                adjn[kc * 2 + 0] = *(const float4_t*)&adj_r[j0 + 64 + kc * 32 + coff];
                adjn[kc * 2 + 1] = *(const float4_t*)&adj_r[j0 + 64 + kc * 32 + coff + 4];
            }
        }
        float4_t s2v[4];
        #pragma unroll
        for (int kc = 0; kc < 2; ++kc) {
            s2v[kc * 2 + 0] = *(const float4_t*)&s2_b[j0 + kc * 32 + coff];
            s2v[kc * 2 + 1] = *(const float4_t*)&s2_b[j0 + kc * 32 + coff + 4];
        }
        half8 afrag[2];
        #pragma unroll
        for (int kc = 0; kc < 2; ++kc) {
            #pragma unroll
            for (int hh = 0; hh < 2; ++hh) {
                float4_t av = adjc[kc * 2 + hh];
                float4_t sv = s2v[kc * 2 + hh];
                #pragma unroll
                for (int c = 0; c < 4; ++c) {
                    float x   = s1v + sv[c];
                    float e   = x > 0.f ? x : 0.2f * x;
                    float p   = av[c] > 0.f ? __expf(av[c] * e - mhat) : 0.f;
                    _Float16 q = (_Float16)p;
                    afrag[kc][hh * 4 + c] = q;
                    psum += (float)q;         // l from fp16-rounded p (matches MFMA)
                }
            }
        }
        #pragma unroll
        for (int nt = 0; nt < 8; ++nt) {
            #pragma unroll
            for (int kc = 0; kc < 2; ++kc) {
                half8 bfrag = *(const half8*)&hT_b[(size_t)(nt * 16 + ln15) * 4096 + j0 + kc * 32 + coff];
                acc[nt] = __builtin_amdgcn_mfma_f32_16x16x32_f16(afrag[kc], bfrag, acc[nt], 0, 0, 0);
            }
        }
        #pragma unroll
        for (int q2 = 0; q2 < 4; ++q2) adjc[q2] = adjn[q2];
    }
    // l: reduce the 4 quads' partial sums for each row
    psum += __shfl_xor(psum, 16);
    psum += __shfl_xor(psum, 32);
    const size_t growb = (size_t)b * 4096 + rowb;
    if (lane < 16) part_l[(size_t)sp * 16384 + growb + lane] = psum;
    float* pacc = part_acc + (size_t)sp * 16384 * 128;
    #pragma unroll
    for (int nt = 0; nt < 8; ++nt) {
        #pragma unroll
        for (int reg = 0; reg < 4; ++reg) {
            pacc[(growb + quad * 4 + reg) * 128 + nt * 16 + ln15] = acc[nt][reg];
        }
    }
}

// ---------------- Kernel E: sum 4 j-split partials, normalize, elu -----------
__global__ __launch_bounds__(256) void k_combine(const float* __restrict__ part_acc,
                                                 const float* __restrict__ part_l,
                                                 float* __restrict__ out) {
    const int idx = blockIdx.x * 256 + threadIdx.x;   // 0..524287
    const int e0  = idx * 4;
    const int gr  = e0 >> 7;
    float l = part_l[gr] + part_l[16384 + gr] + part_l[32768 + gr] + part_l[49152 + gr];
    float4_t a0 = *(const float4_t*)&part_acc[e0];
    float4_t a1 = *(const float4_t*)&part_acc[2097152 + e0];
    float4_t a2 = *(const float4_t*)&part_acc[4194304 + e0];
    float4_t a3 = *(const float4_t*)&part_acc[6291456 + e0];
    float4_t s  = (a0 + a1) + (a2 + a3);
    float rl = 1.f / l;
    float4_t o;
    #pragma unroll
    for (int c = 0; c < 4; ++c) {
        float v = s[c] * rl;
        o[c] = v > 0.f ? v : expm1f(v);
    }
    *(float4_t*)&((float*)out)[e0] = o;
}

extern "C" void kernel_launch(void* const* d_in, const int* in_sizes, int n_in,
                              void* d_out, int out_size, void* d_ws, size_t ws_size,
                              hipStream_t stream) {
    const float* inp = (const float*)d_in[0];   // (4,4096,256)
    const float* adj = (const float*)d_in[1];   // (4,4096,4096)
    const float* W   = (const float*)d_in[2];   // (256,128)
    const float* a   = (const float*)d_in[3];   // (256,1)
    float* out = (float*)d_out;                 // (4,4096,128)

    char* wsb = (char*)d_ws;
    _Float16* hT       = (_Float16*)(wsb);                // 4 MB
    float*    s1       = (float*)(wsb + 4194304);         // 64 KB
    float*    s2       = (float*)(wsb + 4259840);         // 64 KB
    float*    s2max    = (float*)(wsb + 4325376);         // 256 B
    float*    part_l   = (float*)(wsb + 4325632);         // 256 KB
    float*    part_acc = (float*)(wsb + 4587776);         // 32 MB (total ~36.4 MB)

    hipLaunchKernelGGL(k_prep,    dim3(512),  dim3(256), 0, stream, inp, W, a, s1, s2, hT);
    hipLaunchKernelGGL(k_s2max,   dim3(4),    dim3(256), 0, stream, s2, s2max);
    hipLaunchKernelGGL(k_flash,   dim3(1024), dim3(256), 0, stream, adj, hT, s1, s2, s2max,
                       part_acc, part_l);
    hipLaunchKernelGGL(k_combine, dim3(2048), dim3(256), 0, stream, part_acc, part_l, out);
}

// Round 3
// 442.172 us; speedup vs baseline: 1.2025x; 1.1642x over previous
//
#include <hip/hip_runtime.h>
#include <math.h>

typedef float    float4_t __attribute__((ext_vector_type(4)));
typedef _Float16 half8    __attribute__((ext_vector_type(8)));

// ---------------- Kernel P: fused h-GEMM + s1/s2 + hT(fp16) ------------------
__global__ __launch_bounds__(256) void k_prep(const float* __restrict__ inp,
                                              const float* __restrict__ W,
                                              const float* __restrict__ a,
                                              float* __restrict__ s1,
                                              float* __restrict__ s2,
                                              _Float16* __restrict__ hT) {
    __shared__ float sA[32 * 68];
    __shared__ float sW[64 * 128];
    const int t   = threadIdx.x;
    const int gr0 = blockIdx.x * 32;          // global row base (0..16383)
    const int b   = gr0 >> 12;                // batch
    const int f0  = (t & 15) * 8;
    const int r0  = (t >> 4) * 2;
    float4_t acc0[2] = {}; float4_t acc1[2] = {};
    for (int kc = 0; kc < 4; ++kc) {
        __syncthreads();
        #pragma unroll
        for (int it = 0; it < 2; ++it) {      // stage inp 32x64
            int fi = it * 256 + t; int r = fi >> 4; int c = (fi & 15) * 4;
            *(float4_t*)&sA[r * 68 + c] =
                *(const float4_t*)&inp[(size_t)(gr0 + r) * 256 + kc * 64 + c];
        }
        #pragma unroll
        for (int it = 0; it < 8; ++it) {      // stage W 64x128
            int fi = it * 256 + t; int k = fi >> 5; int c = (fi & 31) * 4;
            *(float4_t*)&sW[k * 128 + c] =
                *(const float4_t*)&W[(size_t)(kc * 64 + k) * 128 + c];
        }
        __syncthreads();
        for (int k = 0; k < 64; ++k) {
            float4_t w0 = *(const float4_t*)&sW[k * 128 + f0];
            float4_t w1 = *(const float4_t*)&sW[k * 128 + f0 + 4];
            #pragma unroll
            for (int r = 0; r < 2; ++r) {
                float av = sA[(r0 + r) * 68 + k];
                acc0[r] += av * w0; acc1[r] += av * w1;
            }
        }
    }
    float4_t a1lo = *(const float4_t*)&a[f0];
    float4_t a1hi = *(const float4_t*)&a[f0 + 4];
    float4_t a2lo = *(const float4_t*)&a[128 + f0];
    float4_t a2hi = *(const float4_t*)&a[128 + f0 + 4];
    #pragma unroll
    for (int r = 0; r < 2; ++r) {
        const int row  = gr0 + r0 + r;
        const int rloc = row & 4095;
        #pragma unroll
        for (int c = 0; c < 4; ++c) {
            hT[(size_t)b * (128 * 4096) + (size_t)(f0 + c) * 4096 + rloc]     = (_Float16)acc0[r][c];
            hT[(size_t)b * (128 * 4096) + (size_t)(f0 + 4 + c) * 4096 + rloc] = (_Float16)acc1[r][c];
        }
        float p1 = acc0[r][0]*a1lo[0] + acc0[r][1]*a1lo[1] + acc0[r][2]*a1lo[2] + acc0[r][3]*a1lo[3]
                 + acc1[r][0]*a1hi[0] + acc1[r][1]*a1hi[1] + acc1[r][2]*a1hi[2] + acc1[r][3]*a1hi[3];
        float p2 = acc0[r][0]*a2lo[0] + acc0[r][1]*a2lo[1] + acc0[r][2]*a2lo[2] + acc0[r][3]*a2lo[3]
                 + acc1[r][0]*a2hi[0] + acc1[r][1]*a2hi[1] + acc1[r][2]*a2hi[2] + acc1[r][3]*a2hi[3];
        #pragma unroll
        for (int o = 1; o < 16; o <<= 1) { p1 += __shfl_xor(p1, o); p2 += __shfl_xor(p2, o); }
        if ((t & 15) == 0) { s1[row] = p1; s2[row] = p2; }
    }
}

// ---------------- Kernel M: per-batch s2 max ---------------------------------
__global__ __launch_bounds__(256) void k_s2max(const float* __restrict__ s2,
                                               float* __restrict__ s2max) {
    const int b = blockIdx.x, t = threadIdx.x;
    float m = -INFINITY;
    for (int i = t; i < 4096; i += 256) m = fmaxf(m, s2[b * 4096 + i]);
    #pragma unroll
    for (int o = 1; o < 64; o <<= 1) m = fmaxf(m, __shfl_xor(m, o));
    __shared__ float sm[4];
    if ((t & 63) == 0) sm[t >> 6] = m;
    __syncthreads();
    if (t == 0) s2max[b] = fmaxf(fmaxf(sm[0], sm[1]), fmaxf(sm[2], sm[3]));
}

// ---------------- Kernel F: fixed-max attention + P@H, LDS-staged hT ---------
// Grid 1024 x 256 thr (4 j-splits x 64 row-blocks x 4 batches). Wave = 16 rows.
// hT tile (128f x 64j fp16, 16KB) double-buffered in LDS with xor-chunk
// swizzle (chunk ^= f&7): conflict-free ds_read_b128 / ds_write_b128, and
// coalesced 128B-per-row staging loads. adj prefetched 1 tile ahead in regs.
// mhat_i = max(0, s1_i + max_j s2_j) >= every logit (adj in [0,1)), so
// j-split partials are plain sums; p is built directly in MFMA A-layout.
__global__ __launch_bounds__(256, 4) void k_flash(const float* __restrict__ adj,
                                                  const _Float16* __restrict__ hT,
                                                  const float* __restrict__ s1,
                                                  const float* __restrict__ s2,
                                                  const float* __restrict__ s2max,
                                                  float* __restrict__ part_acc,
                                                  float* __restrict__ part_l) {
    __shared__ _Float16 hbuf[2][128 * 64];    // 2 x 16KB, xor-swizzled chunks

    const int t    = threadIdx.x;
    const int bid  = blockIdx.x;
    const int sp   = bid & 3;                 // j-split
    const int rb   = (bid >> 2) & 63;         // 64-row block within batch
    const int b    = bid >> 8;                // batch
    const int w    = t >> 6, lane = t & 63;
    const int quad = lane >> 4, ln15 = lane & 15;
    const int rowb  = rb * 64 + w * 16;
    const int myrow = rowb + ln15;
    const float*    adj_r = adj + (size_t)b * 4096 * 4096 + (size_t)myrow * 4096;
    const _Float16* hT_b  = hT + (size_t)b * 128 * 4096;
    const float*    s2_b  = s2 + b * 4096;
    const float s1v  = s1[b * 4096 + myrow];
    const float mhat = fmaxf(0.f, s1v + s2max[b]);
    const int jwbase = sp * 1024;
    const int coff   = quad * 8;

    // staging geometry: thread t covers rows f(i)=i*32+(t>>3), j-chunk (t&7)
    const int sf  = t >> 3;                   // 0..31 (row within 32-row group)
    const int sc  = t & 7;                    // source j-chunk (8 halves = 16B)
    const int fb7 = ln15 & 7;                 // bfrag swizzle key (nt*16 = 0 mod 8)

    float4_t acc[8] = {};
    float psum = 0.f;

    // ---- preload tile 0: adj regs + hT -> LDS buf0 ----
    float4_t adjc[4], adjn[4];
    #pragma unroll
    for (int kc = 0; kc < 2; ++kc) {
        adjc[kc * 2 + 0] = *(const float4_t*)&adj_r[jwbase + kc * 32 + coff];
        adjc[kc * 2 + 1] = *(const float4_t*)&adj_r[jwbase + kc * 32 + coff + 4];
    }
    {
        half8 hreg[4];
        #pragma unroll
        for (int i = 0; i < 4; ++i) {
            int f = i * 32 + sf;
            hreg[i] = *(const half8*)&hT_b[(size_t)f * 4096 + jwbase + sc * 8];
        }
        #pragma unroll
        for (int i = 0; i < 4; ++i) {
            int f = i * 32 + sf;
            *(half8*)&hbuf[0][f * 64 + ((sc ^ (f & 7)) << 3)] = hreg[i];
        }
    }
    __syncthreads();

    for (int jt = 0; jt < 16; ++jt) {
        const int cur = jt & 1;
        const int j0  = jwbase + jt * 64;
        half8 hreg[4];
        if (jt < 15) {                        // prefetch tile jt+1
            #pragma unroll
            for (int i = 0; i < 4; ++i) {
                int f = i * 32 + sf;
                hreg[i] = *(const half8*)&hT_b[(size_t)f * 4096 + j0 + 64 + sc * 8];
            }
            #pragma unroll
            for (int kc = 0; kc < 2; ++kc) {
                adjn[kc * 2 + 0] = *(const float4_t*)&adj_r[j0 + 64 + kc * 32 + coff];
                adjn[kc * 2 + 1] = *(const float4_t*)&adj_r[j0 + 64 + kc * 32 + coff + 4];
            }
        }
        // ---- p in registers, MFMA A-layout ----
        half8 afrag[2];
        #pragma unroll
        for (int kc = 0; kc < 2; ++kc) {
            #pragma unroll
            for (int hh = 0; hh < 2; ++hh) {
                float4_t sv = *(const float4_t*)&s2_b[j0 + kc * 32 + coff + hh * 4];
                float4_t av = adjc[kc * 2 + hh];
                #pragma unroll
                for (int c = 0; c < 4; ++c) {
                    float x = s1v + sv[c];
                    float e = x > 0.f ? x : 0.2f * x;
                    float p = av[c] > 0.f ? __expf(av[c] * e - mhat) : 0.f;
                    _Float16 q = (_Float16)p;
                    afrag[kc][hh * 4 + c] = q;
                    psum += (float)q;
                }
            }
        }
        // ---- MFMA: bfrags via swizzled ds_read_b128 ----
        #pragma unroll
        for (int nt = 0; nt < 8; ++nt) {
            #pragma unroll
            for (int kc = 0; kc < 2; ++kc) {
                const int fb = nt * 16 + ln15;
                half8 bfrag = *(const half8*)&hbuf[cur][fb * 64 + ((((kc << 2) + quad) ^ fb7) << 3)];
                acc[nt] = __builtin_amdgcn_mfma_f32_16x16x32_f16(afrag[kc], bfrag, acc[nt], 0, 0, 0);
            }
        }
        // ---- commit next tile to other buffer, swap ----
        if (jt < 15) {
            #pragma unroll
            for (int i = 0; i < 4; ++i) {
                int f = i * 32 + sf;
                *(half8*)&hbuf[1 - cur][f * 64 + ((sc ^ (f & 7)) << 3)] = hreg[i];
            }
            #pragma unroll
            for (int q2 = 0; q2 < 4; ++q2) adjc[q2] = adjn[q2];
        }
        __syncthreads();
    }
    // ---- epilogue ----
    psum += __shfl_xor(psum, 16);
    psum += __shfl_xor(psum, 32);
    const size_t growb = (size_t)b * 4096 + rowb;
    if (lane < 16) part_l[(size_t)sp * 16384 + growb + lane] = psum;
    float* pacc = part_acc + (size_t)sp * 16384 * 128;
    #pragma unroll
    for (int nt = 0; nt < 8; ++nt) {
        #pragma unroll
        for (int reg = 0; reg < 4; ++reg) {
            pacc[(growb + quad * 4 + reg) * 128 + nt * 16 + ln15] = acc[nt][reg];
        }
    }
}

// ---------------- Kernel E: sum 4 j-split partials, normalize, elu -----------
__global__ __launch_bounds__(256) void k_combine(const float* __restrict__ part_acc,
                                                 const float* __restrict__ part_l,
                                                 float* __restrict__ out) {
    const int idx = blockIdx.x * 256 + threadIdx.x;   // 0..524287
    const int e0  = idx * 4;
    const int gr  = e0 >> 7;
    float l = part_l[gr] + part_l[16384 + gr] + part_l[32768 + gr] + part_l[49152 + gr];
    float4_t a0 = *(const float4_t*)&part_acc[e0];
    float4_t a1 = *(const float4_t*)&part_acc[2097152 + e0];
    float4_t a2 = *(const float4_t*)&part_acc[4194304 + e0];
    float4_t a3 = *(const float4_t*)&part_acc[6291456 + e0];
    float4_t s  = (a0 + a1) + (a2 + a3);
    float rl = 1.f / l;
    float4_t o;
    #pragma unroll
    for (int c = 0; c < 4; ++c) {
        float v = s[c] * rl;
        o[c] = v > 0.f ? v : expm1f(v);
    }
    *(float4_t*)&((float*)out)[e0] = o;
}

extern "C" void kernel_launch(void* const* d_in, const int* in_sizes, int n_in,
                              void* d_out, int out_size, void* d_ws, size_t ws_size,
                              hipStream_t stream) {
    const float* inp = (const float*)d_in[0];   // (4,4096,256)
    const float* adj = (const float*)d_in[1];   // (4,4096,4096)
    const float* W   = (const float*)d_in[2];   // (256,128)
    const float* a   = (const float*)d_in[3];   // (256,1)
    float* out = (float*)d_out;                 // (4,4096,128)

    char* wsb = (char*)d_ws;
    _Float16* hT       = (_Float16*)(wsb);                // 4 MB
    float*    s1       = (float*)(wsb + 4194304);         // 64 KB
    float*    s2       = (float*)(wsb + 4259840);         // 64 KB
    float*    s2max    = (float*)(wsb + 4325376);         // 256 B
    float*    part_l   = (float*)(wsb + 4325632);         // 256 KB
    float*    part_acc = (float*)(wsb + 4587776);         // 32 MB (total ~36.4 MB)

    hipLaunchKernelGGL(k_prep,    dim3(512),  dim3(256), 0, stream, inp, W, a, s1, s2, hT);
    hipLaunchKernelGGL(k_s2max,   dim3(4),    dim3(256), 0, stream, s2, s2max);
    hipLaunchKernelGGL(k_flash,   dim3(1024), dim3(256), 0, stream, adj, hT, s1, s2, s2max,
                       part_acc, part_l);
    hipLaunchKernelGGL(k_combine, dim3(2048), dim3(256), 0, stream, part_acc, part_l, out);
}

// Round 4
// 432.552 us; speedup vs baseline: 1.2292x; 1.0222x over previous
//
#include <hip/hip_runtime.h>
#include <math.h>

typedef float    float4_t __attribute__((ext_vector_type(4)));
typedef _Float16 half8    __attribute__((ext_vector_type(8)));
typedef _Float16 half4_t  __attribute__((ext_vector_type(4)));

// ---------------- Kernel P: fused h-GEMM + s1/s2 + hT(fp16) ------------------
__global__ __launch_bounds__(256) void k_prep(const float* __restrict__ inp,
                                              const float* __restrict__ W,
                                              const float* __restrict__ a,
                                              float* __restrict__ s1,
                                              float* __restrict__ s2,
                                              _Float16* __restrict__ hT) {
    __shared__ float sA[32 * 68];
    __shared__ float sW[64 * 128];
    const int t   = threadIdx.x;
    const int gr0 = blockIdx.x * 32;          // global row base (0..16383)
    const int b   = gr0 >> 12;                // batch
    const int f0  = (t & 15) * 8;
    const int r0  = (t >> 4) * 2;
    float4_t acc0[2] = {}; float4_t acc1[2] = {};
    for (int kc = 0; kc < 4; ++kc) {
        __syncthreads();
        #pragma unroll
        for (int it = 0; it < 2; ++it) {      // stage inp 32x64
            int fi = it * 256 + t; int r = fi >> 4; int c = (fi & 15) * 4;
            *(float4_t*)&sA[r * 68 + c] =
                *(const float4_t*)&inp[(size_t)(gr0 + r) * 256 + kc * 64 + c];
        }
        #pragma unroll
        for (int it = 0; it < 8; ++it) {      // stage W 64x128
            int fi = it * 256 + t; int k = fi >> 5; int c = (fi & 31) * 4;
            *(float4_t*)&sW[k * 128 + c] =
                *(const float4_t*)&W[(size_t)(kc * 64 + k) * 128 + c];
        }
        __syncthreads();
        for (int k = 0; k < 64; ++k) {
            float4_t w0 = *(const float4_t*)&sW[k * 128 + f0];
            float4_t w1 = *(const float4_t*)&sW[k * 128 + f0 + 4];
            #pragma unroll
            for (int r = 0; r < 2; ++r) {
                float av = sA[(r0 + r) * 68 + k];
                acc0[r] += av * w0; acc1[r] += av * w1;
            }
        }
    }
    float4_t a1lo = *(const float4_t*)&a[f0];
    float4_t a1hi = *(const float4_t*)&a[f0 + 4];
    float4_t a2lo = *(const float4_t*)&a[128 + f0];
    float4_t a2hi = *(const float4_t*)&a[128 + f0 + 4];
    #pragma unroll
    for (int r = 0; r < 2; ++r) {
        const int row  = gr0 + r0 + r;
        const int rloc = row & 4095;
        #pragma unroll
        for (int c = 0; c < 4; ++c) {
            hT[(size_t)b * (128 * 4096) + (size_t)(f0 + c) * 4096 + rloc]     = (_Float16)acc0[r][c];
            hT[(size_t)b * (128 * 4096) + (size_t)(f0 + 4 + c) * 4096 + rloc] = (_Float16)acc1[r][c];
        }
        float p1 = acc0[r][0]*a1lo[0] + acc0[r][1]*a1lo[1] + acc0[r][2]*a1lo[2] + acc0[r][3]*a1lo[3]
                 + acc1[r][0]*a1hi[0] + acc1[r][1]*a1hi[1] + acc1[r][2]*a1hi[2] + acc1[r][3]*a1hi[3];
        float p2 = acc0[r][0]*a2lo[0] + acc0[r][1]*a2lo[1] + acc0[r][2]*a2lo[2] + acc0[r][3]*a2lo[3]
                 + acc1[r][0]*a2hi[0] + acc1[r][1]*a2hi[1] + acc1[r][2]*a2hi[2] + acc1[r][3]*a2hi[3];
        #pragma unroll
        for (int o = 1; o < 16; o <<= 1) { p1 += __shfl_xor(p1, o); p2 += __shfl_xor(p2, o); }
        if ((t & 15) == 0) { s1[row] = p1; s2[row] = p2; }
    }
}

// ---------------- Kernel M: per-batch s2 max ---------------------------------
__global__ __launch_bounds__(256) void k_s2max(const float* __restrict__ s2,
                                               float* __restrict__ s2max) {
    const int b = blockIdx.x, t = threadIdx.x;
    float m = -INFINITY;
    for (int i = t; i < 4096; i += 256) m = fmaxf(m, s2[b * 4096 + i]);
    #pragma unroll
    for (int o = 1; o < 64; o <<= 1) m = fmaxf(m, __shfl_xor(m, o));
    __shared__ float sm[4];
    if ((t & 63) == 0) sm[t >> 6] = m;
    __syncthreads();
    if (t == 0) s2max[b] = fmaxf(fmaxf(sm[0], sm[1]), fmaxf(sm[2], sm[3]));
}

// ---------------- Kernel F: fixed-max attention + P@H ------------------------
// Grid 1024 x 256 (4 j-splits x 64 row-blocks x 4 batches). Wave = 16 rows.
// adj loads COALESCED (each inst = 4 contiguous 256B row-segments); p routed
// into MFMA A-layout via wave-PRIVATE swizzled LDS pbuf (no barrier, only
// lgkmcnt(0)). hT tile double-buffered in LDS (xor-chunk swizzle) -> one
// barrier/tile. mhat_i = max(0,s1_i+max_j s2_j) bounds every logit, so
// j-split partials are plain sums; l accumulated per-lane, reduced at end.
__global__ __launch_bounds__(256, 4) void k_flash(const float* __restrict__ adj,
                                                  const _Float16* __restrict__ hT,
                                                  const float* __restrict__ s1,
                                                  const float* __restrict__ s2,
                                                  const float* __restrict__ s2max,
                                                  float* __restrict__ part_acc,
                                                  float* __restrict__ part_l) {
    __shared__ _Float16 hbuf[2][128 * 64];    // 32 KB, hT dbuf, xor-swizzled
    __shared__ _Float16 pbuf[4][16 * 64];     // 8 KB, wave-private p tiles

    const int t    = threadIdx.x;
    const int bid  = blockIdx.x;
    const int sp   = bid & 3;                 // j-split
    const int rb   = (bid >> 2) & 63;         // 64-row block within batch
    const int b    = bid >> 8;                // batch
    const int w    = t >> 6, lane = t & 63;
    const int quad = lane >> 4, ln15 = lane & 15;
    const int g    = quad;                    // row-group for p-compute
    const int cl   = ln15;                    // col-lane for p-compute
    const int rowb = rb * 64 + w * 16;        // wave's 16-row base
    const float*    adj_w = adj + (size_t)b * 4096 * 4096 + (size_t)rowb * 4096;
    const _Float16* hT_b  = hT + (size_t)b * 128 * 4096;
    const float*    s2_b  = s2 + b * 4096;
    const float     s2m   = s2max[b];
    const int jwbase = sp * 1024;

    float s1r[4], mh[4];
    #pragma unroll
    for (int L = 0; L < 4; ++L) {
        s1r[L] = s1[b * 4096 + rowb + L * 4 + g];
        mh[L]  = fmaxf(0.f, s1r[L] + s2m);
    }

    // hT staging geometry: thread covers f-rows i*32+(t>>3), j-chunk t&7
    const int sf  = t >> 3;
    const int sc  = t & 7;
    const int fb7 = ln15 & 7;

    float4_t acc[8] = {};
    float4_t psacc = {0.f, 0.f, 0.f, 0.f};

    // ---- preload hT tile 0 ----
    {
        half8 hreg[4];
        #pragma unroll
        for (int i = 0; i < 4; ++i) {
            int f = i * 32 + sf;
            hreg[i] = *(const half8*)&hT_b[(size_t)f * 4096 + jwbase + sc * 8];
        }
        #pragma unroll
        for (int i = 0; i < 4; ++i) {
            int f = i * 32 + sf;
            *(half8*)&hbuf[0][f * 64 + ((sc ^ (f & 7)) << 3)] = hreg[i];
        }
    }
    __syncthreads();

    for (int jt = 0; jt < 16; ++jt) {
        const int cur = jt & 1;
        const int j0  = jwbase + jt * 64;
        // prefetch hT tile jt+1 into regs
        half8 hreg[4];
        if (jt < 15) {
            #pragma unroll
            for (int i = 0; i < 4; ++i) {
                int f = i * 32 + sf;
                hreg[i] = *(const half8*)&hT_b[(size_t)f * 4096 + j0 + 64 + sc * 8];
            }
        }
        // ---- coalesced adj loads: inst L = rows L*4..L*4+3, 256B each ----
        float4_t av[4];
        #pragma unroll
        for (int L = 0; L < 4; ++L)
            av[L] = *(const float4_t*)&adj_w[(size_t)(L * 4 + g) * 4096 + j0 + cl * 4];
        float4_t s2v = *(const float4_t*)&s2_b[j0 + cl * 4];
        // ---- p = exp(adj*leaky(s1+s2) - mhat), write to wave-private pbuf ----
        #pragma unroll
        for (int L = 0; L < 4; ++L) {
            half4_t qv;
            #pragma unroll
            for (int c = 0; c < 4; ++c) {
                float x = s1r[L] + s2v[c];
                float e = x > 0.f ? x : 0.2f * x;
                float p = av[L][c] > 0.f ? __expf(fmaf(av[L][c], e, -mh[L])) : 0.f;
                _Float16 q = (_Float16)p;
                qv[c] = q;
                psacc[L] += (float)q;
            }
            const int r     = L * 4 + g;
            const int c0    = cl * 4;
            const int chunk = (c0 >> 3) ^ (r & 7);
            *(half4_t*)&pbuf[w][r * 64 + chunk * 8 + (c0 & 7)] = qv;
        }
        // wave-private pbuf: writes visible to this wave's reads after lgkmcnt(0)
        asm volatile("s_waitcnt lgkmcnt(0)" ::: "memory");
        // ---- A-frags from pbuf, B-frags from hbuf, MFMA ----
        half8 afrag[2];
        #pragma unroll
        for (int kc = 0; kc < 2; ++kc) {
            const int chunk = ((kc << 2) + quad) ^ (ln15 & 7);
            afrag[kc] = *(const half8*)&pbuf[w][ln15 * 64 + chunk * 8];
        }
        #pragma unroll
        for (int nt = 0; nt < 8; ++nt) {
            #pragma unroll
            for (int kc = 0; kc < 2; ++kc) {
                const int fb = nt * 16 + ln15;
                half8 bfrag = *(const half8*)&hbuf[cur][fb * 64 + ((((kc << 2) + quad) ^ fb7) << 3)];
                acc[nt] = __builtin_amdgcn_mfma_f32_16x16x32_f16(afrag[kc], bfrag, acc[nt], 0, 0, 0);
            }
        }
        // ---- commit hT jt+1 to other buffer ----
        if (jt < 15) {
            #pragma unroll
            for (int i = 0; i < 4; ++i) {
                int f = i * 32 + sf;
                *(half8*)&hbuf[1 - cur][f * 64 + ((sc ^ (f & 7)) << 3)] = hreg[i];
            }
        }
        __syncthreads();
    }
    // ---- epilogue: reduce l within each 16-lane group, write partials ----
    #pragma unroll
    for (int o = 1; o < 16; o <<= 1) {
        #pragma unroll
        for (int L = 0; L < 4; ++L) psacc[L] += __shfl_xor(psacc[L], o);
    }
    const size_t growb = (size_t)b * 4096 + rowb;
    if (cl == 0) {
        #pragma unroll
        for (int L = 0; L < 4; ++L)
            part_l[(size_t)sp * 16384 + growb + L * 4 + g] = psacc[L];
    }
    float* pacc = part_acc + (size_t)sp * 16384 * 128;
    #pragma unroll
    for (int nt = 0; nt < 8; ++nt) {
        #pragma unroll
        for (int reg = 0; reg < 4; ++reg) {
            pacc[(growb + quad * 4 + reg) * 128 + nt * 16 + ln15] = acc[nt][reg];
        }
    }
}

// ---------------- Kernel E: sum 4 j-split partials, normalize, elu -----------
__global__ __launch_bounds__(256) void k_combine(const float* __restrict__ part_acc,
                                                 const float* __restrict__ part_l,
                                                 float* __restrict__ out) {
    const int idx = blockIdx.x * 256 + threadIdx.x;   // 0..524287
    const int e0  = idx * 4;
    const int gr  = e0 >> 7;
    float l = part_l[gr] + part_l[16384 + gr] + part_l[32768 + gr] + part_l[49152 + gr];
    float4_t a0 = *(const float4_t*)&part_acc[e0];
    float4_t a1 = *(const float4_t*)&part_acc[2097152 + e0];
    float4_t a2 = *(const float4_t*)&part_acc[4194304 + e0];
    float4_t a3 = *(const float4_t*)&part_acc[6291456 + e0];
    float4_t s  = (a0 + a1) + (a2 + a3);
    float rl = 1.f / l;
    float4_t o;
    #pragma unroll
    for (int c = 0; c < 4; ++c) {
        float v = s[c] * rl;
        o[c] = v > 0.f ? v : expm1f(v);
    }
    *(float4_t*)&((float*)out)[e0] = o;
}

extern "C" void kernel_launch(void* const* d_in, const int* in_sizes, int n_in,
                              void* d_out, int out_size, void* d_ws, size_t ws_size,
                              hipStream_t stream) {
    const float* inp = (const float*)d_in[0];   // (4,4096,256)
    const float* adj = (const float*)d_in[1];   // (4,4096,4096)
    const float* W   = (const float*)d_in[2];   // (256,128)
    const float* a   = (const float*)d_in[3];   // (256,1)
    float* out = (float*)d_out;                 // (4,4096,128)

    char* wsb = (char*)d_ws;
    _Float16* hT       = (_Float16*)(wsb);                // 4 MB
    float*    s1       = (float*)(wsb + 4194304);         // 64 KB
    float*    s2       = (float*)(wsb + 4259840);         // 64 KB
    float*    s2max    = (float*)(wsb + 4325376);         // 256 B
    float*    part_l   = (float*)(wsb + 4325632);         // 256 KB
    float*    part_acc = (float*)(wsb + 4587776);         // 32 MB (total ~36.4 MB)

    hipLaunchKernelGGL(k_prep,    dim3(512),  dim3(256), 0, stream, inp, W, a, s1, s2, hT);
    hipLaunchKernelGGL(k_s2max,   dim3(4),    dim3(256), 0, stream, s2, s2max);
    hipLaunchKernelGGL(k_flash,   dim3(1024), dim3(256), 0, stream, adj, hT, s1, s2, s2max,
                       part_acc, part_l);
    hipLaunchKernelGGL(k_combine, dim3(2048), dim3(256), 0, stream, part_acc, part_l, out);
}